// Round 3
// baseline (900.489 us; speedup 1.0000x reference)
//
#include <hip/hip_runtime.h>

#define N_NODES 100000
#define N_EDGES 640000
#define HIDDEN  128
#define N_USERS 1000
#define CAP     64   // max in-degree bucket capacity (Poisson(6.4): P(>64) ~ 0)

using u16 = unsigned short;
using u32 = unsigned int;

using short8  = __attribute__((ext_vector_type(8))) short;  // 8 bf16 (4 VGPR) MFMA frag
using floatx4 = __attribute__((ext_vector_type(4))) float;  // 4 f32 acc frag

__device__ __forceinline__ u16 f2bf(float f) {
  u32 u = __float_as_uint(f);
  u32 r = u + 0x7FFFu + ((u >> 16) & 1u);   // RNE
  return (u16)(r >> 16);
}
__device__ __forceinline__ u32 pack2bf(float a, float b) {
  return (u32)f2bf(a) | ((u32)f2bf(b) << 16);
}
__device__ __forceinline__ float bflo2f(u32 v) { return __uint_as_float(v << 16); }

// ============ linearity refactor ============
// pred = S^2 X (W1 W2 Wp) + (S 1)(b1^T W2 Wp) + 1 (b2^T Wp + bp^T)
// Wc = W1W2Wp [128 x 1000] (bf16, BT layout), u = b1 W2 Wp [1000], v = b2 Wp + bp [1000]

// ---------------- fused prep: cast X, weighted in-degree, T1 = W1@W2 / t1 = b1@W2 ----------------
// blocks [0, 6250): cast emb f32 -> bf16 (8 elems/thread)
// blocks [6250, 8750): deg[col] += w (atomics)
// blocks [8750, 8815): T1[k][c] = sum_j W1[k][j] W2[j][c]; t1[c] = sum_j b1[j] W2[j][c]
__global__ __launch_bounds__(256)
void prep_kernel(const float* __restrict__ emb, u16* __restrict__ xb,
                 const int* __restrict__ ecol, const float* __restrict__ ew,
                 float* __restrict__ deg,
                 const float* __restrict__ W1, const float* __restrict__ b1,
                 const float* __restrict__ W2,
                 float* __restrict__ T1, float* __restrict__ t1) {
  int b = blockIdx.x;
  if (b < 6250) {
    int i = b * 256 + threadIdx.x;              // < 1,600,000 = M*16
    const float4* s4 = (const float4*)(emb + (size_t)i * 8);
    float4 lo = s4[0], hi = s4[1];
    uint4 o;
    o.x = pack2bf(lo.x, lo.y); o.y = pack2bf(lo.z, lo.w);
    o.z = pack2bf(hi.x, hi.y); o.w = pack2bf(hi.z, hi.w);
    ((uint4*)xb)[i] = o;
  } else if (b < 8750) {
    int i = (b - 6250) * 256 + threadIdx.x;     // < 640,000 = E
    atomicAdd(&deg[ecol[i]], ew[i]);
  } else {
    int idx = (b - 8750) * 256 + threadIdx.x;
    if (idx >= 129 * 128) return;
    int k = idx >> 7, c = idx & 127;
    const float* src = (k < 128) ? (W1 + (size_t)k * 128) : b1;
    float s = 0.f;
    for (int j = 0; j < 128; ++j) s += src[j] * W2[(size_t)j * 128 + c];
    if (k < 128) T1[(size_t)k * 128 + c] = s;
    else         t1[c] = s;
  }
}

// ---------------- fused stage 2: bucket (with on-the-fly rsqrt(deg)) + WcT + u,v ----------------
// blocks [0, 2500): bucket edges into per-target CAP slots, norm computed from deg directly
// blocks [2500, 3012): WcT[c][k] = bf16(sum_l T1[k][l] Wp[l][c]), c in [0,1024) zero-padded
// blocks [3012, 3020): u[c] = t1 @ Wp[:,c] ; v[c] = b2 @ Wp[:,c] + bp[c]
__global__ __launch_bounds__(256)
void stage2_kernel(const int* __restrict__ erow, const int* __restrict__ ecol,
                   const float* __restrict__ ew, const float* __restrict__ deg,
                   int* __restrict__ counts, int2* __restrict__ pairs,
                   const float* __restrict__ T1, const float* __restrict__ t1,
                   const float* __restrict__ b2, const float* __restrict__ Wp,
                   const float* __restrict__ bp,
                   u16* __restrict__ WcT, float* __restrict__ u, float* __restrict__ v) {
  int b = blockIdx.x;
  if (b < 2500) {
    int i = b * 256 + threadIdx.x;              // < 640,000 = E
    int r = erow[i], c = ecol[i];
    float dr = deg[r], dc = deg[c];
    float nr = dr > 0.f ? rsqrtf(dr) : 0.f;
    float nc = dc > 0.f ? rsqrtf(dc) : 0.f;
    int pos = atomicAdd(&counts[c], 1);
    if (pos < CAP)
      pairs[((size_t)c << 6) + (size_t)pos] = make_int2(r, __float_as_int(nr * ew[i] * nc));
  } else if (b < 3012) {
    int idx = (b - 2500) * 256 + threadIdx.x;   // < 131072 = 1024*128
    int c = idx >> 7, k = idx & 127;
    float s = 0.f;
    if (c < N_USERS)
      for (int l = 0; l < 128; ++l) s += T1[(size_t)k * 128 + l] * Wp[(size_t)l * N_USERS + c];
    WcT[idx] = f2bf(s);
  } else {
    int idx = (b - 3012) * 256 + threadIdx.x;
    if (idx >= 2 * N_USERS) return;
    if (idx < N_USERS) {
      float s = 0.f;
      for (int j = 0; j < 128; ++j) s += t1[j] * Wp[(size_t)j * N_USERS + idx];
      u[idx] = s;
    } else {
      int c = idx - N_USERS;
      float s = bp[c];
      for (int j = 0; j < 128; ++j) s += b2[j] * Wp[(size_t)j * N_USERS + c];
      v[c] = s;
    }
  }
}

// ---------------- aggregation: out[n] = bf16( sum_e norm*h[src] ) ----------------
// one wave per node; lane e (e < cnt) preloads edge e's (src,norm).
// Paired-edge: per trip, lanes 0-31 handle edge 2t, lanes 32-63 edge 2t+1, each lane
// gathers 8 B (4 bf16) of the 256 B source row. Padding edges have w = 0 (no remainder).
// Cross-half combine at the end via 4x shfl_xor(32); lanes 0-31 store 8 B each.
// S1OUT: also emit s1[n] = sum of norms (wave-reduce of preloaded wv).
template<bool S1OUT>
__global__ __launch_bounds__(256)
void agg_kernel(const u16* __restrict__ hb, const int* __restrict__ counts,
                const int2* __restrict__ pairs, float* __restrict__ s1,
                u16* __restrict__ out, int M) {
  int wid  = threadIdx.x >> 6;
  int lane = threadIdx.x & 63;
  int n = blockIdx.x * 4 + wid;
  if (n >= M) return;
  int cnt = counts[n];
  cnt = cnt < CAP ? cnt : CAP;
  int2 my = make_int2(0, 0);
  if (lane < cnt) my = pairs[((size_t)n << 6) + lane];   // predicated: lanes >= cnt carry w=0
  int   sv = my.x;
  float wv = __int_as_float(my.y);
  const uint2* h8 = (const uint2*)hb;                    // row = 32 x 8 B
  int half = lane >> 5, l5 = lane & 31;
  float a0 = 0.f, a1 = 0.f, a2 = 0.f, a3 = 0.f;
  int trips = (cnt + 1) >> 1;
  int t = 0;
  for (; t + 2 <= trips; t += 2) {
    int e0 = 2 * t + half, e1 = 2 * t + 2 + half;        // max index 63 (cnt<=64)
    int   s0 = __shfl(sv, e0), s1_ = __shfl(sv, e1);
    float w0 = __shfl(wv, e0), w1  = __shfl(wv, e1);
    uint2 h0 = h8[((size_t)s0  << 5) + l5];
    uint2 h1 = h8[((size_t)s1_ << 5) + l5];
    a0 += w0 * bflo2f(h0.x & 0xFFFFu); a1 += w0 * __uint_as_float(h0.x & 0xFFFF0000u);
    a2 += w0 * bflo2f(h0.y & 0xFFFFu); a3 += w0 * __uint_as_float(h0.y & 0xFFFF0000u);
    a0 += w1 * bflo2f(h1.x & 0xFFFFu); a1 += w1 * __uint_as_float(h1.x & 0xFFFF0000u);
    a2 += w1 * bflo2f(h1.y & 0xFFFFu); a3 += w1 * __uint_as_float(h1.y & 0xFFFF0000u);
  }
  for (; t < trips; ++t) {
    int e = 2 * t + half;
    int   s = __shfl(sv, e);
    float w = __shfl(wv, e);
    uint2 h = h8[((size_t)s << 5) + l5];
    a0 += w * bflo2f(h.x & 0xFFFFu); a1 += w * __uint_as_float(h.x & 0xFFFF0000u);
    a2 += w * bflo2f(h.y & 0xFFFFu); a3 += w * __uint_as_float(h.y & 0xFFFF0000u);
  }
  a0 += __shfl_xor(a0, 32); a1 += __shfl_xor(a1, 32);
  a2 += __shfl_xor(a2, 32); a3 += __shfl_xor(a3, 32);
  if (S1OUT) {
    float tt = wv;
    for (int o = 32; o; o >>= 1) tt += __shfl_xor(tt, o);
    if (lane == 0) s1[n] = tt;
  }
  if (half == 0) {
    uint2 o;
    o.x = pack2bf(a0, a1);
    o.y = pack2bf(a2, a3);
    ((uint2*)out)[((size_t)n << 5) + l5] = o;
  }
}

// ---------------- final MFMA GEMM: out[M x 1000] = A[M x 128] @ WcT^T + s1*u + v ----------------
// Each block owns a FULL row strip: 128 rows x 1024 cols. A tile read once from HBM into
// LDS (32 KB, XOR-swizzled); loop over 8 column chunks of 128, B fragments loaded directly
// from global (WcT = 256 KB, L2/L3-resident, reused by all 782 blocks). One syncthreads
// total; normal (cached) stores so L2 merges the 64 B half-line segments (output row
// stride 4000 B is 32 B-misaligned; NT stores forfeited write-coalescing: +33% WRITE_SIZE).
__global__ __launch_bounds__(256, 3)
void gemm_final(const u16* __restrict__ A, const u16* __restrict__ BT,
                const float* __restrict__ s1, const float* __restrict__ u,
                const float* __restrict__ vv, float* __restrict__ outf, int M) {
  __shared__ u16 As[128 * 128];
  const int m0 = blockIdx.x * 128;
  const int tid = threadIdx.x;

  // stage A tile: 2048 chunks of 16 B; chunk c of row r goes to column-chunk c^(r&15)
  for (int i = 0; i < 8; ++i) {
    int chunk = tid + i * 256;
    int row = chunk >> 4;
    int c   = chunk & 15;
    int sw  = ((c ^ (row & 15)) << 3);
    int gr  = m0 + row;
    uint4 av = {0u, 0u, 0u, 0u};
    if (gr < M) av = *(const uint4*)(A + ((size_t)gr << 7) + (c << 3));
    *(uint4*)(&As[(row << 7) + sw]) = av;
  }
  __syncthreads();

  const int wid  = tid >> 6, lane = tid & 63;
  const int wr = (wid >> 1) << 6;       // wave row origin within block tile (2x2 waves)
  const int wc = (wid & 1) << 6;        // wave col origin within the 128-col chunk
  const int lm = lane & 15, quad = lane >> 4;

  // hoist s1 for this thread's 16 output rows (fixed across all column chunks)
  float sr[4][4];
  for (int i = 0; i < 4; ++i)
    for (int r = 0; r < 4; ++r) {
      int row = m0 + wr + i * 16 + quad * 4 + r;
      sr[i][r] = (row < M) ? s1[row] : 0.f;
    }

  for (int nc = 0; nc < 8; ++nc) {
    const int n0 = nc * 128;
    floatx4 acc[4][4] = {};
    for (int ks = 0; ks < 4; ++ks) {
      int cks = ks * 4 + quad;          // 16B-chunk index along K for this lane
      int sw  = ((cks ^ lm) << 3);
      short8 a[4], b[4];
      for (int i = 0; i < 4; ++i)
        a[i] = *(const short8*)(&As[((wr + i * 16 + lm) << 7) + sw]);
      for (int j = 0; j < 4; ++j)       // B direct from global (L2-hot, 16 B/lane)
        b[j] = *(const short8*)(BT + ((size_t)(n0 + wc + j * 16 + lm) << 7) + (cks << 3));
      for (int i = 0; i < 4; ++i)
        for (int j = 0; j < 4; ++j)
          acc[i][j] = __builtin_amdgcn_mfma_f32_16x16x32_bf16(a[i], b[j], acc[i][j], 0, 0, 0);
    }

    // epilogue: D[row = quad*4 + r][col = lm] per 16x16 tile (m89-verified layout)
    float uc[4], vc[4];
    int   colv[4];
    bool  ok[4];
    for (int j = 0; j < 4; ++j) {
      int col = n0 + wc + j * 16 + lm;
      colv[j] = col;
      ok[j]   = col < N_USERS;
      uc[j]   = ok[j] ? u[col]  : 0.f;
      vc[j]   = ok[j] ? vv[col] : 0.f;
    }
    for (int i = 0; i < 4; ++i) {
      int rb = m0 + wr + i * 16 + quad * 4;
      for (int j = 0; j < 4; ++j) {
        if (ok[j]) {
          for (int r = 0; r < 4; ++r) {
            int row = rb + r;
            if (row < M)
              outf[(size_t)row * N_USERS + colv[j]] = acc[i][j][r] + sr[i][r] * uc[j] + vc[j];
          }
        }
      }
    }
  }
}

// ---------------- launch ----------------
extern "C" void kernel_launch(void* const* d_in, const int* in_sizes, int n_in,
                              void* d_out, int out_size, void* d_ws, size_t ws_size,
                              hipStream_t stream) {
  const int*   eidx = (const int*)d_in[0];
  const int*   erow = eidx;
  const int*   ecol = eidx + N_EDGES;
  const float* ew   = (const float*)d_in[1];
  const float* emb  = (const float*)d_in[2];
  const float* W1   = (const float*)d_in[3];
  const float* b1   = (const float*)d_in[4];
  const float* W2   = (const float*)d_in[5];
  const float* b2   = (const float*)d_in[6];
  const float* Wp   = (const float*)d_in[7];
  const float* bp   = (const float*)d_in[8];
  float* out = (float*)d_out;

  const int M = N_NODES;

  // workspace carve (all 128B-aligned sections)
  char* p = (char*)d_ws;
  float* deg    = (float*)p;  p += 400128;                 // 100000 f32
  int*   counts = (int*)p;    p += 400128;                 // 100000 i32 (adjacent to deg: one memset)
  float* s1     = (float*)p;  p += 400128;                 // S*1 (row-sum of norms)
  int2*  pairs  = (int2*)p;   p += (size_t)M * CAP * 8;    // 51.2 MB interleaved (src, norm)
  u16*   Xb     = (u16*)p;    p += (size_t)M * 128 * 2;    // 25.6 MB (X bf16, later z = S^2 X)
  u16*   g      = (u16*)p;    p += (size_t)M * 128 * 2;    // 25.6 MB (S X)
  float* T1     = (float*)p;  p += 128 * 128 * 4;          // W1@W2 f32
  float* t1     = (float*)p;  p += 512;                    // b1@W2 f32
  u16*   WcT    = (u16*)p;    p += 1024 * 128 * 2;         // (W1W2Wp)^T bf16, padded to 1024 cols
  float* uvec   = (float*)p;  p += 4096;                   // b1W2Wp
  float* vvec   = (float*)p;  p += 4096;                   // b2Wp + bp

  hipMemsetAsync(deg, 0, 400128 + 400128, stream);  // deg + counts

  // stage 1: cast + deg + W1@W2 (independent, fused)
  prep_kernel<<<8815, 256, 0, stream>>>(emb, Xb, ecol, ew, deg, W1, b1, W2, T1, t1);
  // stage 2: bucket (rsqrt on the fly) + WcT + u,v (all depend only on stage 1)
  stage2_kernel<<<3020, 256, 0, stream>>>(erow, ecol, ew, deg, counts, pairs,
                                          T1, t1, b2, Wp, bp, WcT, uvec, vvec);

  // z = S (S X)  (two aggregation passes; s1 = S*1 emitted by the first)
  agg_kernel<true ><<<(M + 3) / 4, 256, 0, stream>>>(Xb, counts, pairs, s1, g, M);
  agg_kernel<false><<<(M + 3) / 4, 256, 0, stream>>>(g,  counts, pairs, nullptr, Xb, M);

  // predictions = z @ Wc + s1*u + v  (one block per 128-row strip)
  const int mt = (M + 127) / 128;  // 782
  gemm_final<<<mt, 256, 0, stream>>>(Xb, WcT, s1, uvec, vvec, out, M);
}

// Round 4
// 699.379 us; speedup vs baseline: 1.2876x; 1.2876x over previous
//
#include <hip/hip_runtime.h>

#define N_NODES 100000
#define N_EDGES 640000
#define HIDDEN  128
#define N_USERS 1000
#define CAP     64   // max in-degree bucket capacity (Poisson(6.4): P(>64) ~ 0)

using u16 = unsigned short;
using u32 = unsigned int;

using short8  = __attribute__((ext_vector_type(8))) short;  // 8 bf16 (4 VGPR) MFMA frag
using floatx4 = __attribute__((ext_vector_type(4))) float;  // 4 f32 acc frag

__device__ __forceinline__ u16 f2bf(float f) {
  u32 u = __float_as_uint(f);
  u32 r = u + 0x7FFFu + ((u >> 16) & 1u);   // RNE
  return (u16)(r >> 16);
}
__device__ __forceinline__ u32 pack2bf(float a, float b) {
  return (u32)f2bf(a) | ((u32)f2bf(b) << 16);
}
__device__ __forceinline__ float bflo2f(u32 v) { return __uint_as_float(v << 16); }

// ============ linearity refactor ============
// pred = S^2 X (W1 W2 Wp) + (S 1)(b1^T W2 Wp) + 1 (b2^T Wp + bp^T)
// Wc = W1W2Wp [128 x 1000] (bf16, BT layout), u = b1 W2 Wp [1000], v = b2 Wp + bp [1000]

// ---------------- fused prep: cast X, weighted in-degree, T1 = W1@W2 / t1 = b1@W2 ----------------
// blocks [0, 6250): cast emb f32 -> bf16 (8 elems/thread)
// blocks [6250, 8750): deg[col] += w (atomics)
// blocks [8750, 8815): T1[k][c] = sum_j W1[k][j] W2[j][c]; t1[c] = sum_j b1[j] W2[j][c]
__global__ __launch_bounds__(256)
void prep_kernel(const float* __restrict__ emb, u16* __restrict__ xb,
                 const int* __restrict__ ecol, const float* __restrict__ ew,
                 float* __restrict__ deg,
                 const float* __restrict__ W1, const float* __restrict__ b1,
                 const float* __restrict__ W2,
                 float* __restrict__ T1, float* __restrict__ t1) {
  int b = blockIdx.x;
  if (b < 6250) {
    int i = b * 256 + threadIdx.x;              // < 1,600,000 = M*16
    const float4* s4 = (const float4*)(emb + (size_t)i * 8);
    float4 lo = s4[0], hi = s4[1];
    uint4 o;
    o.x = pack2bf(lo.x, lo.y); o.y = pack2bf(lo.z, lo.w);
    o.z = pack2bf(hi.x, hi.y); o.w = pack2bf(hi.z, hi.w);
    ((uint4*)xb)[i] = o;
  } else if (b < 8750) {
    int i = (b - 6250) * 256 + threadIdx.x;     // < 640,000 = E
    atomicAdd(&deg[ecol[i]], ew[i]);
  } else {
    int idx = (b - 8750) * 256 + threadIdx.x;
    if (idx >= 129 * 128) return;
    int k = idx >> 7, c = idx & 127;
    const float* src = (k < 128) ? (W1 + (size_t)k * 128) : b1;
    float s = 0.f;
    for (int j = 0; j < 128; ++j) s += src[j] * W2[(size_t)j * 128 + c];
    if (k < 128) T1[(size_t)k * 128 + c] = s;
    else         t1[c] = s;
  }
}

// ---------------- fused stage 2: bucket (with on-the-fly rsqrt(deg)) + WcT + u,v ----------------
// blocks [0, 2500): bucket edges into per-target CAP slots, norm computed from deg directly
// blocks [2500, 3012): WcT[c][k] = bf16(sum_l T1[k][l] Wp[l][c]), c in [0,1024) zero-padded
// blocks [3012, 3020): u[c] = t1 @ Wp[:,c] ; v[c] = b2 @ Wp[:,c] + bp[c]
__global__ __launch_bounds__(256)
void stage2_kernel(const int* __restrict__ erow, const int* __restrict__ ecol,
                   const float* __restrict__ ew, const float* __restrict__ deg,
                   int* __restrict__ counts, int2* __restrict__ pairs,
                   const float* __restrict__ T1, const float* __restrict__ t1,
                   const float* __restrict__ b2, const float* __restrict__ Wp,
                   const float* __restrict__ bp,
                   u16* __restrict__ WcT, float* __restrict__ u, float* __restrict__ v) {
  int b = blockIdx.x;
  if (b < 2500) {
    int i = b * 256 + threadIdx.x;              // < 640,000 = E
    int r = erow[i], c = ecol[i];
    float dr = deg[r], dc = deg[c];
    float nr = dr > 0.f ? rsqrtf(dr) : 0.f;
    float nc = dc > 0.f ? rsqrtf(dc) : 0.f;
    int pos = atomicAdd(&counts[c], 1);
    if (pos < CAP)
      pairs[((size_t)c << 6) + (size_t)pos] = make_int2(r, __float_as_int(nr * ew[i] * nc));
  } else if (b < 3012) {
    int idx = (b - 2500) * 256 + threadIdx.x;   // < 131072 = 1024*128
    int c = idx >> 7, k = idx & 127;
    float s = 0.f;
    if (c < N_USERS)
      for (int l = 0; l < 128; ++l) s += T1[(size_t)k * 128 + l] * Wp[(size_t)l * N_USERS + c];
    WcT[idx] = f2bf(s);
  } else {
    int idx = (b - 3012) * 256 + threadIdx.x;
    if (idx >= 2 * N_USERS) return;
    if (idx < N_USERS) {
      float s = 0.f;
      for (int j = 0; j < 128; ++j) s += t1[j] * Wp[(size_t)j * N_USERS + idx];
      u[idx] = s;
    } else {
      int c = idx - N_USERS;
      float s = bp[c];
      for (int j = 0; j < 128; ++j) s += b2[j] * Wp[(size_t)j * N_USERS + c];
      v[c] = s;
    }
  }
}

// ---------------- aggregation: out[n] = bf16( sum_e norm*h[src] ) ----------------
// one wave per node; lane e (e < cnt) preloads edge e's (src,norm).
// Paired-edge: per trip, lanes 0-31 handle edge 2t, lanes 32-63 edge 2t+1, each lane
// gathers 8 B (4 bf16) of the 256 B source row. Padding edges have w = 0 (no remainder).
// Cross-half combine at the end via 4x shfl_xor(32); lanes 0-31 store 8 B each.
// S1OUT: also emit s1[n] = sum of norms (wave-reduce of preloaded wv).
template<bool S1OUT>
__global__ __launch_bounds__(256)
void agg_kernel(const u16* __restrict__ hb, const int* __restrict__ counts,
                const int2* __restrict__ pairs, float* __restrict__ s1,
                u16* __restrict__ out, int M) {
  int wid  = threadIdx.x >> 6;
  int lane = threadIdx.x & 63;
  int n = blockIdx.x * 4 + wid;
  if (n >= M) return;
  int cnt = counts[n];
  cnt = cnt < CAP ? cnt : CAP;
  int2 my = make_int2(0, 0);
  if (lane < cnt) my = pairs[((size_t)n << 6) + lane];   // predicated: lanes >= cnt carry w=0
  int   sv = my.x;
  float wv = __int_as_float(my.y);
  const uint2* h8 = (const uint2*)hb;                    // row = 32 x 8 B
  int half = lane >> 5, l5 = lane & 31;
  float a0 = 0.f, a1 = 0.f, a2 = 0.f, a3 = 0.f;
  int trips = (cnt + 1) >> 1;
  int t = 0;
  for (; t + 2 <= trips; t += 2) {
    int e0 = 2 * t + half, e1 = 2 * t + 2 + half;        // max index 63 (cnt<=64)
    int   s0 = __shfl(sv, e0), s1_ = __shfl(sv, e1);
    float w0 = __shfl(wv, e0), w1  = __shfl(wv, e1);
    uint2 h0 = h8[((size_t)s0  << 5) + l5];
    uint2 h1 = h8[((size_t)s1_ << 5) + l5];
    a0 += w0 * bflo2f(h0.x & 0xFFFFu); a1 += w0 * __uint_as_float(h0.x & 0xFFFF0000u);
    a2 += w0 * bflo2f(h0.y & 0xFFFFu); a3 += w0 * __uint_as_float(h0.y & 0xFFFF0000u);
    a0 += w1 * bflo2f(h1.x & 0xFFFFu); a1 += w1 * __uint_as_float(h1.x & 0xFFFF0000u);
    a2 += w1 * bflo2f(h1.y & 0xFFFFu); a3 += w1 * __uint_as_float(h1.y & 0xFFFF0000u);
  }
  for (; t < trips; ++t) {
    int e = 2 * t + half;
    int   s = __shfl(sv, e);
    float w = __shfl(wv, e);
    uint2 h = h8[((size_t)s << 5) + l5];
    a0 += w * bflo2f(h.x & 0xFFFFu); a1 += w * __uint_as_float(h.x & 0xFFFF0000u);
    a2 += w * bflo2f(h.y & 0xFFFFu); a3 += w * __uint_as_float(h.y & 0xFFFF0000u);
  }
  a0 += __shfl_xor(a0, 32); a1 += __shfl_xor(a1, 32);
  a2 += __shfl_xor(a2, 32); a3 += __shfl_xor(a3, 32);
  if (S1OUT) {
    float tt = wv;
    for (int o = 32; o; o >>= 1) tt += __shfl_xor(tt, o);
    if (lane == 0) s1[n] = tt;
  }
  if (half == 0) {
    uint2 o;
    o.x = pack2bf(a0, a1);
    o.y = pack2bf(a2, a3);
    ((uint2*)out)[((size_t)n << 5) + l5] = o;
  }
}

// ---------------- final MFMA GEMM: out[M x 1000] = A[M x 128] @ WcT^T + s1*u + v ----------------
// Round-2 structure (A+B staged in LDS, block tile 128x128, grid mt x 8 n-fastest) with a
// coalesced epilogue: acc + s1*u + v computed in regs, transposed through LDS (reusing the
// 64 KB A/B buffer), then stored as float4 — each wave-instr writes 2 contiguous 512 B row
// segments (full-line coverage, cached stores; scalar-dword/NT stores were the 2.1 TB/s cap).
__global__ __launch_bounds__(256, 2)
void gemm_final(const u16* __restrict__ A, const u16* __restrict__ BT,
                const float* __restrict__ s1, const float* __restrict__ u,
                const float* __restrict__ vv, float* __restrict__ outf, int M) {
  __shared__ u16 smem[2 * 128 * 128];   // 64 KB: As|Bs, later reused as 128x128 f32 chunk
  u16* As = smem;
  u16* Bs = smem + 128 * 128;
  const int m0 = (blockIdx.x >> 3) * 128;
  const int n0 = (blockIdx.x & 7) * 128;
  const int tid = threadIdx.x;

  // cooperative staging: 2048 chunks of 16B; chunk c of row r goes to column-chunk c^(r&15)
  for (int i = 0; i < 8; ++i) {
    int chunk = tid + i * 256;
    int row = chunk >> 4;
    int c   = chunk & 15;
    int sw  = ((c ^ (row & 15)) << 3);
    int gr  = m0 + row;
    uint4 av = {0u, 0u, 0u, 0u};
    if (gr < M) av = *(const uint4*)(A + ((size_t)gr << 7) + (c << 3));
    *(uint4*)(&As[(row << 7) + sw]) = av;
    uint4 bv = *(const uint4*)(BT + ((size_t)(n0 + row) << 7) + (c << 3));
    *(uint4*)(&Bs[(row << 7) + sw]) = bv;
  }
  __syncthreads();

  const int wid  = tid >> 6, lane = tid & 63;
  const int wr = (wid >> 1) << 6;       // wave row origin within block tile
  const int wc = (wid & 1) << 6;        // wave col origin
  const int lm = lane & 15, quad = lane >> 4;

  floatx4 acc[4][4] = {};
  for (int ks = 0; ks < 4; ++ks) {
    int cks = ks * 4 + quad;            // 16B-chunk index along K for this lane
    int sw  = ((cks ^ lm) << 3);
    short8 a[4], b[4];
    for (int i = 0; i < 4; ++i)
      a[i] = *(const short8*)(&As[((wr + i * 16 + lm) << 7) + sw]);
    for (int j = 0; j < 4; ++j)
      b[j] = *(const short8*)(&Bs[((wc + j * 16 + lm) << 7) + sw]);
    for (int i = 0; i < 4; ++i)
      for (int j = 0; j < 4; ++j)
        acc[i][j] = __builtin_amdgcn_mfma_f32_16x16x32_bf16(a[i], b[j], acc[i][j], 0, 0, 0);
  }

  // rank-1 terms in regs (D[row = quad*4 + r][col = lm] per 16x16 tile, m89-verified)
  float uc[4], vc[4];
  for (int j = 0; j < 4; ++j) {
    int col = n0 + wc + j * 16 + lm;
    bool ok = col < N_USERS;            // cols >= 1000: value never stored
    uc[j] = ok ? u[col]  : 0.f;
    vc[j] = ok ? vv[col] : 0.f;
  }
  float sr[4][4];
  for (int i = 0; i < 4; ++i)
    for (int r = 0; r < 4; ++r) {
      int row = m0 + wr + i * 16 + quad * 4 + r;
      sr[i][r] = (row < M) ? s1[row] : 0.f;
    }

  __syncthreads();                      // all waves done reading As/Bs
  float* Os = (float*)smem;             // 128 x 128 f32 = 64 KB
  for (int i = 0; i < 4; ++i)
    for (int j = 0; j < 4; ++j)
      for (int r = 0; r < 4; ++r) {
        int lrow = wr + i * 16 + quad * 4 + r;
        int lcol = wc + j * 16 + lm;
        Os[(lrow << 7) + lcol] = acc[i][j][r] + sr[i][r] * uc[j] + vc[j];
      }
  __syncthreads();

  // cooperative store: 4096 float4 (16/thread); wave-instr = 2 rows x 512 B contiguous
  for (int k = 0; k < 16; ++k) {
    int f   = k * 256 + tid;
    int row = f >> 5;                   // local row, 32 float4 per row
    int c4  = f & 31;
    int gr  = m0 + row;
    int col = n0 + (c4 << 2);
    if (gr < M && col < N_USERS) {      // col multiple of 4, 1000 % 4 == 0 -> full float4 valid
      float4 val = *(const float4*)(Os + (row << 7) + (c4 << 2));
      *(float4*)(outf + (size_t)gr * N_USERS + col) = val;
    }
  }
}

// ---------------- launch ----------------
extern "C" void kernel_launch(void* const* d_in, const int* in_sizes, int n_in,
                              void* d_out, int out_size, void* d_ws, size_t ws_size,
                              hipStream_t stream) {
  const int*   eidx = (const int*)d_in[0];
  const int*   erow = eidx;
  const int*   ecol = eidx + N_EDGES;
  const float* ew   = (const float*)d_in[1];
  const float* emb  = (const float*)d_in[2];
  const float* W1   = (const float*)d_in[3];
  const float* b1   = (const float*)d_in[4];
  const float* W2   = (const float*)d_in[5];
  const float* b2   = (const float*)d_in[6];
  const float* Wp   = (const float*)d_in[7];
  const float* bp   = (const float*)d_in[8];
  float* out = (float*)d_out;

  const int M = N_NODES;

  // workspace carve (all 128B-aligned sections)
  char* p = (char*)d_ws;
  float* deg    = (float*)p;  p += 400128;                 // 100000 f32
  int*   counts = (int*)p;    p += 400128;                 // 100000 i32 (adjacent to deg: one memset)
  float* s1     = (float*)p;  p += 400128;                 // S*1 (row-sum of norms)
  int2*  pairs  = (int2*)p;   p += (size_t)M * CAP * 8;    // 51.2 MB interleaved (src, norm)
  u16*   Xb     = (u16*)p;    p += (size_t)M * 128 * 2;    // 25.6 MB (X bf16, later z = S^2 X)
  u16*   g      = (u16*)p;    p += (size_t)M * 128 * 2;    // 25.6 MB (S X)
  float* T1     = (float*)p;  p += 128 * 128 * 4;          // W1@W2 f32
  float* t1     = (float*)p;  p += 512;                    // b1@W2 f32
  u16*   WcT    = (u16*)p;    p += 1024 * 128 * 2;         // (W1W2Wp)^T bf16, padded to 1024 cols
  float* uvec   = (float*)p;  p += 4096;                   // b1W2Wp
  float* vvec   = (float*)p;  p += 4096;                   // b2Wp + bp

  hipMemsetAsync(deg, 0, 400128 + 400128, stream);  // deg + counts

  // stage 1: cast + deg + W1@W2 (independent, fused)
  prep_kernel<<<8815, 256, 0, stream>>>(emb, Xb, ecol, ew, deg, W1, b1, W2, T1, t1);
  // stage 2: bucket (rsqrt on the fly) + WcT + u,v (all depend only on stage 1)
  stage2_kernel<<<3020, 256, 0, stream>>>(erow, ecol, ew, deg, counts, pairs,
                                          T1, t1, b2, Wp, bp, WcT, uvec, vvec);

  // z = S (S X)  (two aggregation passes; s1 = S*1 emitted by the first)
  agg_kernel<true ><<<(M + 3) / 4, 256, 0, stream>>>(Xb, counts, pairs, s1, g, M);
  agg_kernel<false><<<(M + 3) / 4, 256, 0, stream>>>(g,  counts, pairs, nullptr, Xb, M);

  // predictions = z @ Wc + s1*u + v
  const int mt = (M + 127) / 128;  // 782
  gemm_final<<<mt * 8, 256, 0, stream>>>(Xb, WcT, s1, uvec, vvec, out, M);
}

// Round 5
// 668.626 us; speedup vs baseline: 1.3468x; 1.0460x over previous
//
#include <hip/hip_runtime.h>

#define N_NODES 100000
#define N_EDGES 640000
#define HIDDEN  128
#define N_USERS 1000
#define CAP     64   // max in-degree bucket capacity (Poisson(6.4): P(>64) ~ 0)

using u16 = unsigned short;
using u32 = unsigned int;

using short8  = __attribute__((ext_vector_type(8))) short;  // 8 bf16 (4 VGPR) MFMA frag
using floatx4 = __attribute__((ext_vector_type(4))) float;  // 4 f32 acc frag

__device__ __forceinline__ u16 f2bf(float f) {
  u32 u = __float_as_uint(f);
  u32 r = u + 0x7FFFu + ((u >> 16) & 1u);   // RNE
  return (u16)(r >> 16);
}
__device__ __forceinline__ u32 pack2bf(float a, float b) {
  return (u32)f2bf(a) | ((u32)f2bf(b) << 16);
}
__device__ __forceinline__ float bflo2f(u32 v) { return __uint_as_float(v << 16); }

// ============ linearity refactor ============
// pred = S^2 X (W1 W2 Wp) + (S 1)(b1^T W2 Wp) + 1 (b2^T Wp + bp^T)
// Wc = W1W2Wp [128 x 1000] (bf16, BT layout), u = b1 W2 Wp [1000], v = b2 Wp + bp [1000]

// ---------------- fused prep: cast X, weighted in-degree, T1 = W1@W2 / t1 = b1@W2 ----------------
// blocks [0, 6250): cast emb f32 -> bf16 (8 elems/thread)
// blocks [6250, 8750): deg[col] += w (atomics)
// blocks [8750, 8815): T1[k][c] = sum_j W1[k][j] W2[j][c]; t1[c] = sum_j b1[j] W2[j][c]
__global__ __launch_bounds__(256)
void prep_kernel(const float* __restrict__ emb, u16* __restrict__ xb,
                 const int* __restrict__ ecol, const float* __restrict__ ew,
                 float* __restrict__ deg,
                 const float* __restrict__ W1, const float* __restrict__ b1,
                 const float* __restrict__ W2,
                 float* __restrict__ T1, float* __restrict__ t1) {
  int b = blockIdx.x;
  if (b < 6250) {
    int i = b * 256 + threadIdx.x;              // < 1,600,000 = M*16
    const float4* s4 = (const float4*)(emb + (size_t)i * 8);
    float4 lo = s4[0], hi = s4[1];
    uint4 o;
    o.x = pack2bf(lo.x, lo.y); o.y = pack2bf(lo.z, lo.w);
    o.z = pack2bf(hi.x, hi.y); o.w = pack2bf(hi.z, hi.w);
    ((uint4*)xb)[i] = o;
  } else if (b < 8750) {
    int i = (b - 6250) * 256 + threadIdx.x;     // < 640,000 = E
    atomicAdd(&deg[ecol[i]], ew[i]);
  } else {
    int idx = (b - 8750) * 256 + threadIdx.x;
    if (idx >= 129 * 128) return;
    int k = idx >> 7, c = idx & 127;
    const float* src = (k < 128) ? (W1 + (size_t)k * 128) : b1;
    float s = 0.f;
    for (int j = 0; j < 128; ++j) s += src[j] * W2[(size_t)j * 128 + c];
    if (k < 128) T1[(size_t)k * 128 + c] = s;
    else         t1[c] = s;
  }
}

// ---------------- fused stage 2: bucket (with on-the-fly rsqrt(deg)) + WcT + u,v ----------------
// blocks [0, 2500): bucket edges into per-target CAP slots, norm computed from deg directly
// blocks [2500, 3012): WcT[c][k] = bf16(sum_l T1[k][l] Wp[l][c]), c in [0,1024) zero-padded
// blocks [3012, 3020): u[c] = t1 @ Wp[:,c] ; v[c] = b2 @ Wp[:,c] + bp[c]
__global__ __launch_bounds__(256)
void stage2_kernel(const int* __restrict__ erow, const int* __restrict__ ecol,
                   const float* __restrict__ ew, const float* __restrict__ deg,
                   int* __restrict__ counts, int2* __restrict__ pairs,
                   const float* __restrict__ T1, const float* __restrict__ t1,
                   const float* __restrict__ b2, const float* __restrict__ Wp,
                   const float* __restrict__ bp,
                   u16* __restrict__ WcT, float* __restrict__ u, float* __restrict__ v) {
  int b = blockIdx.x;
  if (b < 2500) {
    int i = b * 256 + threadIdx.x;              // < 640,000 = E
    int r = erow[i], c = ecol[i];
    float dr = deg[r], dc = deg[c];
    float nr = dr > 0.f ? rsqrtf(dr) : 0.f;
    float nc = dc > 0.f ? rsqrtf(dc) : 0.f;
    int pos = atomicAdd(&counts[c], 1);
    if (pos < CAP)
      pairs[((size_t)c << 6) + (size_t)pos] = make_int2(r, __float_as_int(nr * ew[i] * nc));
  } else if (b < 3012) {
    int idx = (b - 2500) * 256 + threadIdx.x;   // < 131072 = 1024*128
    int c = idx >> 7, k = idx & 127;
    float s = 0.f;
    if (c < N_USERS)
      for (int l = 0; l < 128; ++l) s += T1[(size_t)k * 128 + l] * Wp[(size_t)l * N_USERS + c];
    WcT[idx] = f2bf(s);
  } else {
    int idx = (b - 3012) * 256 + threadIdx.x;
    if (idx >= 2 * N_USERS) return;
    if (idx < N_USERS) {
      float s = 0.f;
      for (int j = 0; j < 128; ++j) s += t1[j] * Wp[(size_t)j * N_USERS + idx];
      u[idx] = s;
    } else {
      int c = idx - N_USERS;
      float s = bp[c];
      for (int j = 0; j < 128; ++j) s += b2[j] * Wp[(size_t)j * N_USERS + c];
      v[c] = s;
    }
  }
}

// ---------------- aggregation: out[n] = bf16( sum_e norm*h[src] ) ----------------
// one wave per node; lane e (e < cnt) preloads edge e's (src,norm).
// Paired-edge: per trip, lanes 0-31 handle edge 2t, lanes 32-63 edge 2t+1, each lane
// gathers 8 B (4 bf16) of the 256 B source row. Padding edges have w = 0 (no remainder).
// Cross-half combine at the end via 4x shfl_xor(32); lanes 0-31 store 8 B each.
// S1OUT: also emit s1[n] = sum of norms (wave-reduce of preloaded wv).
template<bool S1OUT>
__global__ __launch_bounds__(256)
void agg_kernel(const u16* __restrict__ hb, const int* __restrict__ counts,
                const int2* __restrict__ pairs, float* __restrict__ s1,
                u16* __restrict__ out, int M) {
  int wid  = threadIdx.x >> 6;
  int lane = threadIdx.x & 63;
  int n = blockIdx.x * 4 + wid;
  if (n >= M) return;
  int cnt = counts[n];
  cnt = cnt < CAP ? cnt : CAP;
  int2 my = make_int2(0, 0);
  if (lane < cnt) my = pairs[((size_t)n << 6) + lane];   // predicated: lanes >= cnt carry w=0
  int   sv = my.x;
  float wv = __int_as_float(my.y);
  const uint2* h8 = (const uint2*)hb;                    // row = 32 x 8 B
  int half = lane >> 5, l5 = lane & 31;
  float a0 = 0.f, a1 = 0.f, a2 = 0.f, a3 = 0.f;
  int trips = (cnt + 1) >> 1;
  int t = 0;
  for (; t + 2 <= trips; t += 2) {
    int e0 = 2 * t + half, e1 = 2 * t + 2 + half;        // max index 63 (cnt<=64)
    int   s0 = __shfl(sv, e0), s1_ = __shfl(sv, e1);
    float w0 = __shfl(wv, e0), w1  = __shfl(wv, e1);
    uint2 h0 = h8[((size_t)s0  << 5) + l5];
    uint2 h1 = h8[((size_t)s1_ << 5) + l5];
    a0 += w0 * bflo2f(h0.x & 0xFFFFu); a1 += w0 * __uint_as_float(h0.x & 0xFFFF0000u);
    a2 += w0 * bflo2f(h0.y & 0xFFFFu); a3 += w0 * __uint_as_float(h0.y & 0xFFFF0000u);
    a0 += w1 * bflo2f(h1.x & 0xFFFFu); a1 += w1 * __uint_as_float(h1.x & 0xFFFF0000u);
    a2 += w1 * bflo2f(h1.y & 0xFFFFu); a3 += w1 * __uint_as_float(h1.y & 0xFFFF0000u);
  }
  for (; t < trips; ++t) {
    int e = 2 * t + half;
    int   s = __shfl(sv, e);
    float w = __shfl(wv, e);
    uint2 h = h8[((size_t)s << 5) + l5];
    a0 += w * bflo2f(h.x & 0xFFFFu); a1 += w * __uint_as_float(h.x & 0xFFFF0000u);
    a2 += w * bflo2f(h.y & 0xFFFFu); a3 += w * __uint_as_float(h.y & 0xFFFF0000u);
  }
  a0 += __shfl_xor(a0, 32); a1 += __shfl_xor(a1, 32);
  a2 += __shfl_xor(a2, 32); a3 += __shfl_xor(a3, 32);
  if (S1OUT) {
    float tt = wv;
    for (int o = 32; o; o >>= 1) tt += __shfl_xor(tt, o);
    if (lane == 0) s1[n] = tt;
  }
  if (half == 0) {
    uint2 o;
    o.x = pack2bf(a0, a1);
    o.y = pack2bf(a2, a3);
    ((uint2*)out)[((size_t)n << 5) + l5] = o;
  }
}

// ---------------- final MFMA GEMM: out[M x 1000] = A[M x 128] @ WcT^T + s1*u + v ----------------
// LDS = 32 KB (A tile only) -> 4 blocks/CU. B fragments read directly from global
// (WcT = 256 KB, L2-hot per XCD). XCD-grouping swizzle: flat bid = g*64 + n*8 + r with
// m = g*8 + r, so all 8 n-variants of an m-tile share dispatch residue r -> same XCD ->
// A tile fetched into exactly one L2. Epilogue: acc + s1*u + v transposed through the
// (dead) A buffer in two 64-row halves, stored as float4 (2 x 512 B contiguous per
// wave-instr, full-line coverage, cached stores).
__global__ __launch_bounds__(256, 4)
void gemm_final(const u16* __restrict__ A, const u16* __restrict__ BT,
                const float* __restrict__ s1, const float* __restrict__ u,
                const float* __restrict__ vv, float* __restrict__ outf, int M) {
  __shared__ u16 As[128 * 128];         // 32 KB; reused as 64x128 f32 Os after MFMA
  const int bid = blockIdx.x;
  const int g = bid >> 6, w = bid & 63;
  const int mi = g * 8 + (w & 7);       // m-tile index; same residue -> same XCD
  if (mi >= (N_NODES + 127) / 128) return;
  const int m0 = mi << 7;
  const int n0 = (w >> 3) << 7;
  const int tid = threadIdx.x;

  // stage A tile: 2048 chunks of 16 B; chunk c of row r goes to column-chunk c^(r&15)
  for (int i = 0; i < 8; ++i) {
    int chunk = tid + i * 256;
    int row = chunk >> 4;
    int c   = chunk & 15;
    int sw  = ((c ^ (row & 15)) << 3);
    int gr  = m0 + row;
    uint4 av = {0u, 0u, 0u, 0u};
    if (gr < M) av = *(const uint4*)(A + ((size_t)gr << 7) + (c << 3));
    *(uint4*)(&As[(row << 7) + sw]) = av;
  }
  __syncthreads();

  const int wid  = tid >> 6, lane = tid & 63;
  const int wr = (wid >> 1) << 6;       // wave row origin within block tile
  const int wc = (wid & 1) << 6;        // wave col origin
  const int lm = lane & 15, quad = lane >> 4;

  floatx4 acc[4][4] = {};
  for (int ks = 0; ks < 4; ++ks) {
    int cks = ks * 4 + quad;            // 16B-chunk index along K for this lane
    int sw  = ((cks ^ lm) << 3);
    short8 a[4], b[4];
    for (int i = 0; i < 4; ++i)
      a[i] = *(const short8*)(&As[((wr + i * 16 + lm) << 7) + sw]);
    for (int j = 0; j < 4; ++j)         // B direct from global (L2-hot, 16 B/lane)
      b[j] = *(const short8*)(BT + ((size_t)(n0 + wc + j * 16 + lm) << 7) + (cks << 3));
    for (int i = 0; i < 4; ++i)
      for (int j = 0; j < 4; ++j)
        acc[i][j] = __builtin_amdgcn_mfma_f32_16x16x32_bf16(a[i], b[j], acc[i][j], 0, 0, 0);
  }

  // rank-1 terms in regs (D[row = quad*4 + r][col = lm] per 16x16 tile, m89-verified)
  float uc[4], vc[4];
  for (int j = 0; j < 4; ++j) {
    int col = n0 + wc + j * 16 + lm;
    bool ok = col < N_USERS;            // cols >= 1000: value never stored
    uc[j] = ok ? u[col]  : 0.f;
    vc[j] = ok ? vv[col] : 0.f;
  }
  float sr[4][4];
  for (int i = 0; i < 4; ++i)
    for (int r = 0; r < 4; ++r) {
      int row = m0 + wr + i * 16 + quad * 4 + r;
      sr[i][r] = (row < M) ? s1[row] : 0.f;
    }

  __syncthreads();                      // all waves done reading As
  float* Os = (float*)As;               // 64 x 128 f32 = 32 KB
  for (int h = 0; h < 2; ++h) {
    if ((wr >> 6) == h) {               // waves owning block rows [h*64, h*64+64)
      for (int i = 0; i < 4; ++i)
        for (int j = 0; j < 4; ++j)
          for (int r = 0; r < 4; ++r) {
            int lrow = i * 16 + quad * 4 + r;       // wr&63 == 0
            int lcol = wc + j * 16 + lm;
            Os[(lrow << 7) + lcol] = acc[i][j][r] + sr[i][r] * uc[j] + vc[j];
          }
    }
    __syncthreads();
    // store 64 rows: 2048 float4 (8/thread); wave-instr = 2 rows x 512 B contiguous
    for (int k = 0; k < 8; ++k) {
      int f   = k * 256 + tid;
      int row = f >> 5;                 // local row, 32 float4 per row
      int c4  = f & 31;
      int gr  = m0 + h * 64 + row;
      int col = n0 + (c4 << 2);
      if (gr < M && col < N_USERS) {    // col multiple of 4, 1000 % 4 == 0 -> full float4 valid
        float4 val = *(const float4*)(Os + (row << 7) + (c4 << 2));
        *(float4*)(outf + (size_t)gr * N_USERS + col) = val;
      }
    }
    __syncthreads();                    // before next half overwrites Os
  }
}

// ---------------- launch ----------------
extern "C" void kernel_launch(void* const* d_in, const int* in_sizes, int n_in,
                              void* d_out, int out_size, void* d_ws, size_t ws_size,
                              hipStream_t stream) {
  const int*   eidx = (const int*)d_in[0];
  const int*   erow = eidx;
  const int*   ecol = eidx + N_EDGES;
  const float* ew   = (const float*)d_in[1];
  const float* emb  = (const float*)d_in[2];
  const float* W1   = (const float*)d_in[3];
  const float* b1   = (const float*)d_in[4];
  const float* W2   = (const float*)d_in[5];
  const float* b2   = (const float*)d_in[6];
  const float* Wp   = (const float*)d_in[7];
  const float* bp   = (const float*)d_in[8];
  float* out = (float*)d_out;

  const int M = N_NODES;

  // workspace carve (all 128B-aligned sections)
  char* p = (char*)d_ws;
  float* deg    = (float*)p;  p += 400128;                 // 100000 f32
  int*   counts = (int*)p;    p += 400128;                 // 100000 i32 (adjacent to deg: one memset)
  float* s1     = (float*)p;  p += 400128;                 // S*1 (row-sum of norms)
  int2*  pairs  = (int2*)p;   p += (size_t)M * CAP * 8;    // 51.2 MB interleaved (src, norm)
  u16*   Xb     = (u16*)p;    p += (size_t)M * 128 * 2;    // 25.6 MB (X bf16, later z = S^2 X)
  u16*   g      = (u16*)p;    p += (size_t)M * 128 * 2;    // 25.6 MB (S X)
  float* T1     = (float*)p;  p += 128 * 128 * 4;          // W1@W2 f32
  float* t1     = (float*)p;  p += 512;                    // b1@W2 f32
  u16*   WcT    = (u16*)p;    p += 1024 * 128 * 2;         // (W1W2Wp)^T bf16, padded to 1024 cols
  float* uvec   = (float*)p;  p += 4096;                   // b1W2Wp
  float* vvec   = (float*)p;  p += 4096;                   // b2Wp + bp

  hipMemsetAsync(deg, 0, 400128 + 400128, stream);  // deg + counts

  // stage 1: cast + deg + W1@W2 (independent, fused)
  prep_kernel<<<8815, 256, 0, stream>>>(emb, Xb, ecol, ew, deg, W1, b1, W2, T1, t1);
  // stage 2: bucket (rsqrt on the fly) + WcT + u,v (all depend only on stage 1)
  stage2_kernel<<<3020, 256, 0, stream>>>(erow, ecol, ew, deg, counts, pairs,
                                          T1, t1, b2, Wp, bp, WcT, uvec, vvec);

  // z = S (S X)  (two aggregation passes; s1 = S*1 emitted by the first)
  agg_kernel<true ><<<(M + 3) / 4, 256, 0, stream>>>(Xb, counts, pairs, s1, g, M);
  agg_kernel<false><<<(M + 3) / 4, 256, 0, stream>>>(g,  counts, pairs, nullptr, Xb, M);

  // predictions = z @ Wc + s1*u + v
  // grid: 98 m-groups x (8 n x 8 m-residue) = 6272 blocks (guarded past 782 m-tiles)
  gemm_final<<<98 * 64, 256, 0, stream>>>(Xb, WcT, s1, uvec, vvec, out, M);
}